// Round 1
// baseline (2723.652 us; speedup 1.0000x reference)
//
#include <hip/hip_runtime.h>
#include <hip/hip_bf16.h>
#include <math.h>

#define N_NODES 50000
#define N_EDGES 800000
#define DIM 64
#define NLAYERS 3
#define BN_EPS 1e-5f
#define INV_SQRT2 0.7071067811865475f

// ---------------- helpers ----------------

__device__ __forceinline__ float gelu_f(float v) {
    // exact (erf) GELU, matches torch/jax approximate=False
    return 0.5f * v * (1.0f + erff(v * INV_SQRT2));
}

__device__ __forceinline__ float bf2f(unsigned short u) {
    union { unsigned int i; float f; } t; t.i = ((unsigned int)u) << 16; return t.f;
}
__device__ __forceinline__ unsigned short f2bf(float f) {
    union { float f; unsigned int i; } t; t.f = f;
    unsigned int x = t.i;
    unsigned int r = (x >> 16) & 1u;
    x += 0x7fffu + r;          // round-to-nearest-even
    return (unsigned short)(x >> 16);
}

// emb buffer element access, templated on storage type (float or ushort=bf16)
__device__ __forceinline__ float4 emb_load4(const float* p) { return *(const float4*)p; }
__device__ __forceinline__ float4 emb_load4(const unsigned short* p) {
    ushort4 u = *(const ushort4*)p;
    float4 r; r.x = bf2f(u.x); r.y = bf2f(u.y); r.z = bf2f(u.z); r.w = bf2f(u.w);
    return r;
}
__device__ __forceinline__ void emb_store4(float* p, float4 v) { *(float4*)p = v; }
__device__ __forceinline__ void emb_store4(unsigned short* p, float4 v) {
    ushort4 u; u.x = f2bf(v.x); u.y = f2bf(v.y); u.z = f2bf(v.z); u.w = f2bf(v.w);
    *(ushort4*)p = u;
}

// ---------------- kernel 0: bond encoder GEMM: emb = attr @ W + b ----------------
// 64 rows per block, 256 threads; W (64x64) staged in LDS.
template <typename T>
__global__ __launch_bounds__(256) void be_gemm(const float* __restrict__ attr,
                                               const float* __restrict__ W,
                                               const float* __restrict__ b,
                                               T* __restrict__ out, int rows) {
    __shared__ float Wl[64][64];    // [k][c]
    __shared__ float tile[64][65];
    int tid = threadIdx.x;
    for (int i = tid; i < 4096; i += 256) Wl[i >> 6][i & 63] = W[i];
    int row0 = blockIdx.x * 64;
    for (int i = tid; i < 4096; i += 256) {
        int r = i >> 6, c = i & 63;
        int gr = row0 + r;
        tile[r][c] = (gr < rows) ? attr[(long long)gr * DIM + c] : 0.0f;
    }
    __syncthreads();
    int r = tid & 63, c0 = (tid >> 6) * 16;
    float acc[16];
#pragma unroll
    for (int j = 0; j < 16; j++) acc[j] = b[c0 + j];
    for (int k = 0; k < 64; k++) {
        float hv = tile[r][k];
#pragma unroll
        for (int j = 0; j < 16; j++) acc[j] += hv * Wl[k][c0 + j];
    }
    __syncthreads();
#pragma unroll
    for (int j = 0; j < 16; j++) tile[r][c0 + j] = acc[j];
    __syncthreads();
    // coalesced vectorized store
    for (int i = tid; i < 1024; i += 256) {   // 1024 float4s
        int rr = i >> 4, c4 = (i & 15) * 4;
        int gr = row0 + rr;
        if (gr < rows) {
            float4 v = make_float4(tile[rr][c4], tile[rr][c4 + 1], tile[rr][c4 + 2], tile[rr][c4 + 3]);
            emb_store4(&out[(long long)gr * DIM + c4], v);
        }
    }
}

// ---------------- kernel 1: agg = (1+eps_l)*x ; zero BN stats ----------------
__global__ __launch_bounds__(256) void init_agg(const float* __restrict__ x,
                                                float* __restrict__ agg,
                                                const float* __restrict__ eps, int layer,
                                                float* __restrict__ stats) {
    int i = blockIdx.x * 256 + threadIdx.x;
    float e1 = 1.0f + eps[layer];
    if (i < N_NODES * DIM / 4) {
        float4 v = ((const float4*)x)[i];
        v.x *= e1; v.y *= e1; v.z *= e1; v.w *= e1;
        ((float4*)agg)[i] = v;
    }
    if (blockIdx.x == 0 && threadIdx.x < 128) stats[threadIdx.x] = 0.0f;
}

// ---------------- kernel 2: edge gather + GELU + scatter-add ----------------
// 16 threads per edge, float4 each.
template <typename T>
__global__ __launch_bounds__(256) void edge_kernel(const float* __restrict__ x,
                                                   const int* __restrict__ ei,
                                                   const T* __restrict__ emb,
                                                   float* __restrict__ agg) {
    int idx = blockIdx.x * 256 + threadIdx.x;
    int e = idx >> 4;
    if (e >= N_EDGES) return;
    int p4 = (idx & 15) * 4;
    int s = ei[e];
    int d = ei[N_EDGES + e];
    float4 xv = *(const float4*)(x + (long long)s * DIM + p4);
    float4 ev = emb_load4(emb + (long long)e * DIM + p4);
    float m0 = gelu_f(xv.x + ev.x);
    float m1 = gelu_f(xv.y + ev.y);
    float m2 = gelu_f(xv.z + ev.z);
    float m3 = gelu_f(xv.w + ev.w);
    float* ar = agg + (long long)d * DIM + p4;
    unsafeAtomicAdd(ar + 0, m0);
    unsafeAtomicAdd(ar + 1, m1);
    unsafeAtomicAdd(ar + 2, m2);
    unsafeAtomicAdd(ar + 3, m3);
}

// ---------------- kernel 3: per-node MLP + BN-stat accumulation ----------------
__global__ __launch_bounds__(256) void mlp_kernel(const float* __restrict__ h_in,
                                                  const float* __restrict__ W1,
                                                  const float* __restrict__ b1,
                                                  const float* __restrict__ W2,
                                                  const float* __restrict__ b2,
                                                  float* __restrict__ h2,
                                                  float* __restrict__ stats) {
    __shared__ float W1l[64][64];
    __shared__ float W2l[64][64];
    __shared__ float tileA[64][65];
    __shared__ float tileB[64][65];
    __shared__ float sred[4][64];
    __shared__ float sred2[4][64];
    int tid = threadIdx.x;
    for (int i = tid; i < 4096; i += 256) {
        W1l[i >> 6][i & 63] = W1[i];
        W2l[i >> 6][i & 63] = W2[i];
    }
    int row0 = blockIdx.x * 64;
    for (int i = tid; i < 4096; i += 256) {
        int r = i >> 6, c = i & 63;
        int gr = row0 + r;
        tileA[r][c] = (gr < N_NODES) ? h_in[(long long)gr * DIM + c] : 0.0f;
    }
    __syncthreads();
    int r = tid & 63, q = tid >> 6, c0 = q * 16;
    float acc[16];
#pragma unroll
    for (int j = 0; j < 16; j++) acc[j] = b1[c0 + j];
    for (int k = 0; k < 64; k++) {
        float hv = tileA[r][k];
#pragma unroll
        for (int j = 0; j < 16; j++) acc[j] += hv * W1l[k][c0 + j];
    }
#pragma unroll
    for (int j = 0; j < 16; j++) tileB[r][c0 + j] = gelu_f(acc[j]);
    __syncthreads();
#pragma unroll
    for (int j = 0; j < 16; j++) acc[j] = b2[c0 + j];
    for (int k = 0; k < 64; k++) {
        float hv = tileB[r][k];
#pragma unroll
        for (int j = 0; j < 16; j++) acc[j] += hv * W2l[k][c0 + j];
    }
    __syncthreads();
#pragma unroll
    for (int j = 0; j < 16; j++) tileA[r][c0 + j] = acc[j];
    __syncthreads();
    int nvalid = min(64, N_NODES - row0);
    // coalesced write-out
    for (int i = tid; i < 1024; i += 256) {
        int rr = i >> 4, c4 = (i & 15) * 4;
        int gr = row0 + rr;
        if (gr < N_NODES) {
            float4 v = make_float4(tileA[rr][c4], tileA[rr][c4 + 1], tileA[rr][c4 + 2], tileA[rr][c4 + 3]);
            *(float4*)(h2 + (long long)gr * DIM + c4) = v;
        }
    }
    // BN partial stats: feature f = tid&63, quarter q sums 16 rows
    float s = 0.0f, s2 = 0.0f;
    int f = tid & 63;
    int rend = min(q * 16 + 16, nvalid);
    for (int rr = q * 16; rr < rend; rr++) {
        float v = tileA[rr][f];
        s += v; s2 += v * v;
    }
    sred[q][f] = s; sred2[q][f] = s2;
    __syncthreads();
    if (tid < 64) {
        float ts = sred[0][tid] + sred[1][tid] + sred[2][tid] + sred[3][tid];
        float ts2 = sred2[0][tid] + sred2[1][tid] + sred2[2][tid] + sred2[3][tid];
        unsafeAtomicAdd(&stats[tid], ts);
        unsafeAtomicAdd(&stats[64 + tid], ts2);
    }
}

// ---------------- kernel 4: BN + GELU + residual ----------------
__global__ __launch_bounds__(256) void bn_kernel(const float* __restrict__ x,
                                                 const float* __restrict__ h2,
                                                 const float* __restrict__ stats,
                                                 const float* __restrict__ gamma,
                                                 const float* __restrict__ beta,
                                                 float* __restrict__ out) {
    int i = blockIdx.x * 256 + threadIdx.x;
    if (i >= N_NODES * DIM / 4) return;
    int f4 = i & 15;   // feature group (4 features)
    float4 sum = ((const float4*)stats)[f4];
    float4 sq = ((const float4*)(stats + 64))[f4];
    const float invN = 1.0f / (float)N_NODES;
    float mu0 = sum.x * invN, mu1 = sum.y * invN, mu2 = sum.z * invN, mu3 = sum.w * invN;
    float rs0 = rsqrtf(sq.x * invN - mu0 * mu0 + BN_EPS);
    float rs1 = rsqrtf(sq.y * invN - mu1 * mu1 + BN_EPS);
    float rs2 = rsqrtf(sq.z * invN - mu2 * mu2 + BN_EPS);
    float rs3 = rsqrtf(sq.w * invN - mu3 * mu3 + BN_EPS);
    float4 g = ((const float4*)gamma)[f4];
    float4 bt = ((const float4*)beta)[f4];
    float4 hv = ((const float4*)h2)[i];
    float4 xv = ((const float4*)x)[i];
    float4 o;
    o.x = (xv.x + gelu_f((hv.x - mu0) * rs0 * g.x + bt.x)) * INV_SQRT2;
    o.y = (xv.y + gelu_f((hv.y - mu1) * rs1 * g.y + bt.y)) * INV_SQRT2;
    o.z = (xv.z + gelu_f((hv.z - mu2) * rs2 * g.z + bt.z)) * INV_SQRT2;
    o.w = (xv.w + gelu_f((hv.w - mu3) * rs3 * g.w + bt.w)) * INV_SQRT2;
    ((float4*)out)[i] = o;
}

// ---------------- launch ----------------
extern "C" void kernel_launch(void* const* d_in, const int* in_sizes, int n_in,
                              void* d_out, int out_size, void* d_ws, size_t ws_size,
                              hipStream_t stream) {
    const float* x = (const float*)d_in[0];
    const int* ei = (const int*)d_in[1];
    const float* attr = (const float*)d_in[2];
    const float* W_be = (const float*)d_in[3];
    const float* b_be = (const float*)d_in[4];
    const float* eps = (const float*)d_in[5];
    const float* W1 = (const float*)d_in[6];
    const float* b1 = (const float*)d_in[7];
    const float* W2 = (const float*)d_in[8];
    const float* b2 = (const float*)d_in[9];
    const float* gamma = (const float*)d_in[10];
    const float* beta = (const float*)d_in[11];
    float* out = (float*)d_out;

    const size_t emb_f32_bytes = (size_t)N_EDGES * DIM * 4;
    const size_t emb_bf16_bytes = (size_t)N_EDGES * DIM * 2;
    const size_t node_bytes = (size_t)N_NODES * DIM * 4;
    const size_t rest = 3 * node_bytes + 512;  // agg + h2 + xA + stats
    bool use_f32_emb = (ws_size >= emb_f32_bytes + rest);

    char* ws = (char*)d_ws;
    size_t emb_bytes = use_f32_emb ? emb_f32_bytes : emb_bf16_bytes;
    void* emb = (void*)ws;
    float* agg = (float*)(ws + emb_bytes);
    float* h2 = (float*)(ws + emb_bytes + node_bytes);
    float* xA = (float*)(ws + emb_bytes + 2 * node_bytes);
    float* stats = (float*)(ws + emb_bytes + 3 * node_bytes);

    const int beBlocks = N_EDGES / 64;             // 12500
    const int nodeVecBlocks = (N_NODES * DIM / 4 + 255) / 256;  // 3125
    const int edgeBlocks = N_EDGES * 16 / 256;     // 50000
    const int mlpBlocks = (N_NODES + 63) / 64;     // 782

    if (use_f32_emb) {
        be_gemm<float><<<beBlocks, 256, 0, stream>>>(attr, W_be, b_be, (float*)emb, N_EDGES);
    } else {
        be_gemm<unsigned short><<<beBlocks, 256, 0, stream>>>(attr, W_be, b_be, (unsigned short*)emb, N_EDGES);
    }

    for (int l = 0; l < NLAYERS; l++) {
        const float* xin = (l == 0) ? x : ((l == 1) ? xA : out);
        float* xout = (l == 0) ? xA : out;
        init_agg<<<nodeVecBlocks, 256, 0, stream>>>(xin, agg, eps, l, stats);
        if (use_f32_emb) {
            edge_kernel<float><<<edgeBlocks, 256, 0, stream>>>(xin, ei, (const float*)emb, agg);
        } else {
            edge_kernel<unsigned short><<<edgeBlocks, 256, 0, stream>>>(xin, ei, (const unsigned short*)emb, agg);
        }
        mlp_kernel<<<mlpBlocks, 256, 0, stream>>>(agg, W1 + l * 4096, b1 + l * 64,
                                                  W2 + l * 4096, b2 + l * 64, h2, stats);
        bn_kernel<<<nodeVecBlocks, 256, 0, stream>>>(xin, h2, stats, gamma + l * 64,
                                                     beta + l * 64, xout);
    }
}

// Round 3
// 968.901 us; speedup vs baseline: 2.8111x; 2.8111x over previous
//
#include <hip/hip_runtime.h>
#include <hip/hip_bf16.h>
#include <math.h>

#define N_NODES 50000
#define N_EDGES 800000
#define DIM 64
#define NLAYERS 3
#define BN_EPS 1e-5f
#define INV_SQRT2 0.7071067811865475f

// ---------------- helpers ----------------

__device__ __forceinline__ float gelu_f(float v) {
    // exact (erf) GELU, matches torch/jax approximate=False
    return 0.5f * v * (1.0f + erff(v * INV_SQRT2));
}

__device__ __forceinline__ float bf2f(unsigned short u) {
    union { unsigned int i; float f; } t; t.i = ((unsigned int)u) << 16; return t.f;
}
__device__ __forceinline__ unsigned short f2bf(float f) {
    union { float f; unsigned int i; } t; t.f = f;
    unsigned int x = t.i;
    unsigned int r = (x >> 16) & 1u;
    x += 0x7fffu + r;          // round-to-nearest-even
    return (unsigned short)(x >> 16);
}

__device__ __forceinline__ float emb_elem(const float* p) { return *p; }
__device__ __forceinline__ float emb_elem(const unsigned short* p) { return bf2f(*p); }
__device__ __forceinline__ void emb_store4(float* p, float4 v) { *(float4*)p = v; }
__device__ __forceinline__ void emb_store4(unsigned short* p, float4 v) {
    ushort4 u; u.x = f2bf(v.x); u.y = f2bf(v.y); u.z = f2bf(v.z); u.w = f2bf(v.w);
    *(ushort4*)p = u;
}

// ---------------- CSR build ----------------

__global__ __launch_bounds__(256) void zero_kernel(int* __restrict__ deg) {
    int i = blockIdx.x * 256 + threadIdx.x;
    if (i < N_NODES) deg[i] = 0;
}

__global__ __launch_bounds__(256) void hist_kernel(const int* __restrict__ ei,
                                                   int* __restrict__ deg) {
    int e = blockIdx.x * 256 + threadIdx.x;
    if (e < N_EDGES) atomicAdd(&deg[ei[N_EDGES + e]], 1);
}

// per-block sums of deg (blocks of 256)
__global__ __launch_bounds__(256) void scan_partials(const int* __restrict__ deg,
                                                     int* __restrict__ part) {
    __shared__ int red[256];
    int i = blockIdx.x * 256 + threadIdx.x;
    int v = (i < N_NODES) ? deg[i] : 0;
    red[threadIdx.x] = v; __syncthreads();
    for (int s = 128; s > 0; s >>= 1) {
        if (threadIdx.x < s) red[threadIdx.x] += red[threadIdx.x + s];
        __syncthreads();
    }
    if (threadIdx.x == 0) part[blockIdx.x] = red[0];
}

// single block: exclusive scan of nparts (<256) partials in-place
__global__ __launch_bounds__(256) void scan_top(int* __restrict__ part, int nparts) {
    __shared__ int sh[256];
    int v = (threadIdx.x < nparts) ? part[threadIdx.x] : 0;
    sh[threadIdx.x] = v; __syncthreads();
    for (int s = 1; s < 256; s <<= 1) {
        int t = (threadIdx.x >= s) ? sh[threadIdx.x - s] : 0;
        __syncthreads();
        sh[threadIdx.x] += t;
        __syncthreads();
    }
    if (threadIdx.x < nparts) part[threadIdx.x] = sh[threadIdx.x] - v;  // exclusive
}

// final: row_start = exclusive scan; also init cursor
__global__ __launch_bounds__(256) void scan_final(const int* __restrict__ deg,
                                                  const int* __restrict__ part,
                                                  int* __restrict__ row_start,
                                                  int* __restrict__ cursor) {
    __shared__ int sh[256];
    int i = blockIdx.x * 256 + threadIdx.x;
    int v = (i < N_NODES) ? deg[i] : 0;
    sh[threadIdx.x] = v; __syncthreads();
    for (int s = 1; s < 256; s <<= 1) {
        int t = (threadIdx.x >= s) ? sh[threadIdx.x - s] : 0;
        __syncthreads();
        sh[threadIdx.x] += t;
        __syncthreads();
    }
    int excl = sh[threadIdx.x] - v + part[blockIdx.x];
    if (i < N_NODES) { row_start[i] = excl; cursor[i] = excl; }
    if (i == N_NODES - 1) row_start[N_NODES] = excl + v;  // == E
}

__global__ __launch_bounds__(256) void scatter_kernel(const int* __restrict__ ei,
                                                      int* __restrict__ cursor,
                                                      int* __restrict__ pos_of_edge,
                                                      int* __restrict__ src_sorted) {
    int e = blockIdx.x * 256 + threadIdx.x;
    if (e >= N_EDGES) return;
    int d = ei[N_EDGES + e];
    int pos = atomicAdd(&cursor[d], 1);
    pos_of_edge[e] = pos;
    src_sorted[pos] = ei[e];
}

// ---------------- bond encoder GEMM: emb_sorted[pos[e]] = attr[e] @ W + b ----------------
template <typename T>
__global__ __launch_bounds__(256) void be_gemm(const float* __restrict__ attr,
                                               const float* __restrict__ W,
                                               const float* __restrict__ b,
                                               const int* __restrict__ pos_of_edge,
                                               T* __restrict__ out, int rows) {
    __shared__ float Wl[64][64];    // [k][c]
    __shared__ float tile[64][65];
    __shared__ int posl[64];
    int tid = threadIdx.x;
    for (int i = tid; i < 4096; i += 256) Wl[i >> 6][i & 63] = W[i];
    int row0 = blockIdx.x * 64;
    if (tid < 64 && row0 + tid < rows) posl[tid] = pos_of_edge[row0 + tid];
    for (int i = tid; i < 4096; i += 256) {
        int r = i >> 6, c = i & 63;
        int gr = row0 + r;
        tile[r][c] = (gr < rows) ? attr[(long long)gr * DIM + c] : 0.0f;
    }
    __syncthreads();
    int r = tid & 63, c0 = (tid >> 6) * 16;
    float acc[16];
#pragma unroll
    for (int j = 0; j < 16; j++) acc[j] = b[c0 + j];
    for (int k = 0; k < 64; k++) {
        float hv = tile[r][k];
#pragma unroll
        for (int j = 0; j < 16; j++) acc[j] += hv * Wl[k][c0 + j];
    }
    __syncthreads();
#pragma unroll
    for (int j = 0; j < 16; j++) tile[r][c0 + j] = acc[j];
    __syncthreads();
    // store rows to their CSR position (256B contiguous per row)
    for (int i = tid; i < 1024; i += 256) {   // 1024 float4s
        int rr = i >> 4, c4 = (i & 15) * 4;
        int gr = row0 + rr;
        if (gr < rows) {
            float4 v = make_float4(tile[rr][c4], tile[rr][c4 + 1], tile[rr][c4 + 2], tile[rr][c4 + 3]);
            emb_store4(&out[(long long)posl[rr] * DIM + c4], v);
        }
    }
}

// ---------------- aggregation: one wave per node, one lane per feature ----------------
template <typename T>
__global__ __launch_bounds__(256) void agg_kernel(const float* __restrict__ x,
                                                  const int* __restrict__ row_start,
                                                  const int* __restrict__ src_sorted,
                                                  const T* __restrict__ emb,   // CSR order
                                                  const float* __restrict__ eps, int layer,
                                                  float* __restrict__ hout,
                                                  float* __restrict__ stats) {
    if (blockIdx.x == 0 && threadIdx.x < 128) stats[threadIdx.x] = 0.0f;
    int node = (blockIdx.x * 256 + threadIdx.x) >> 6;
    int lane = threadIdx.x & 63;
    if (node >= N_NODES) return;
    int beg = row_start[node], end = row_start[node + 1];
    float acc = 0.0f;
    int p = beg;
    for (; p + 1 < end; p += 2) {
        int s0 = src_sorted[p];
        int s1 = src_sorted[p + 1];
        float e0 = emb_elem(emb + (long long)p * DIM + lane);
        float e1 = emb_elem(emb + (long long)(p + 1) * DIM + lane);
        float x0 = x[(long long)s0 * DIM + lane];
        float x1 = x[(long long)s1 * DIM + lane];
        acc += gelu_f(x0 + e0);
        acc += gelu_f(x1 + e1);
    }
    if (p < end) {
        int s0 = src_sorted[p];
        float e0 = emb_elem(emb + (long long)p * DIM + lane);
        float x0 = x[(long long)s0 * DIM + lane];
        acc += gelu_f(x0 + e0);
    }
    float e1f = 1.0f + eps[layer];
    hout[(long long)node * DIM + lane] = e1f * x[(long long)node * DIM + lane] + acc;
}

// ---------------- per-node MLP + BN-stat accumulation ----------------
__global__ __launch_bounds__(256) void mlp_kernel(const float* __restrict__ h_in,
                                                  const float* __restrict__ W1,
                                                  const float* __restrict__ b1,
                                                  const float* __restrict__ W2,
                                                  const float* __restrict__ b2,
                                                  float* __restrict__ h2,
                                                  float* __restrict__ stats) {
    __shared__ float W1l[64][64];
    __shared__ float W2l[64][64];
    __shared__ float tileA[64][65];
    __shared__ float tileB[64][65];
    __shared__ float sred[4][64];
    __shared__ float sred2[4][64];
    int tid = threadIdx.x;
    for (int i = tid; i < 4096; i += 256) {
        W1l[i >> 6][i & 63] = W1[i];
        W2l[i >> 6][i & 63] = W2[i];
    }
    int row0 = blockIdx.x * 64;
    for (int i = tid; i < 4096; i += 256) {
        int r = i >> 6, c = i & 63;
        int gr = row0 + r;
        tileA[r][c] = (gr < N_NODES) ? h_in[(long long)gr * DIM + c] : 0.0f;
    }
    __syncthreads();
    int r = tid & 63, q = tid >> 6, c0 = q * 16;
    float acc[16];
#pragma unroll
    for (int j = 0; j < 16; j++) acc[j] = b1[c0 + j];
    for (int k = 0; k < 64; k++) {
        float hv = tileA[r][k];
#pragma unroll
        for (int j = 0; j < 16; j++) acc[j] += hv * W1l[k][c0 + j];
    }
#pragma unroll
    for (int j = 0; j < 16; j++) tileB[r][c0 + j] = gelu_f(acc[j]);
    __syncthreads();
#pragma unroll
    for (int j = 0; j < 16; j++) acc[j] = b2[c0 + j];
    for (int k = 0; k < 64; k++) {
        float hv = tileB[r][k];
#pragma unroll
        for (int j = 0; j < 16; j++) acc[j] += hv * W2l[k][c0 + j];
    }
    __syncthreads();
#pragma unroll
    for (int j = 0; j < 16; j++) tileA[r][c0 + j] = acc[j];
    __syncthreads();
    int nvalid = min(64, N_NODES - row0);
    // coalesced write-out
    for (int i = tid; i < 1024; i += 256) {
        int rr = i >> 4, c4 = (i & 15) * 4;
        int gr = row0 + rr;
        if (gr < N_NODES) {
            float4 v = make_float4(tileA[rr][c4], tileA[rr][c4 + 1], tileA[rr][c4 + 2], tileA[rr][c4 + 3]);
            *(float4*)(h2 + (long long)gr * DIM + c4) = v;
        }
    }
    // BN partial stats: feature f = tid&63, quarter q sums 16 rows
    float s = 0.0f, s2 = 0.0f;
    int f = tid & 63;
    int rend = min(q * 16 + 16, nvalid);
    for (int rr = q * 16; rr < rend; rr++) {
        float v = tileA[rr][f];
        s += v; s2 += v * v;
    }
    sred[q][f] = s; sred2[q][f] = s2;
    __syncthreads();
    if (tid < 64) {
        float ts = sred[0][tid] + sred[1][tid] + sred[2][tid] + sred[3][tid];
        float ts2 = sred2[0][tid] + sred2[1][tid] + sred2[2][tid] + sred2[3][tid];
        unsafeAtomicAdd(&stats[tid], ts);
        unsafeAtomicAdd(&stats[64 + tid], ts2);
    }
}

// ---------------- BN + GELU + residual ----------------
__global__ __launch_bounds__(256) void bn_kernel(const float* __restrict__ x,
                                                 const float* __restrict__ h2,
                                                 const float* __restrict__ stats,
                                                 const float* __restrict__ gamma,
                                                 const float* __restrict__ beta,
                                                 float* __restrict__ out) {
    int i = blockIdx.x * 256 + threadIdx.x;
    if (i >= N_NODES * DIM / 4) return;
    int f4 = i & 15;   // feature group (4 features)
    float4 sum = ((const float4*)stats)[f4];
    float4 sq = ((const float4*)(stats + 64))[f4];
    const float invN = 1.0f / (float)N_NODES;
    float mu0 = sum.x * invN, mu1 = sum.y * invN, mu2 = sum.z * invN, mu3 = sum.w * invN;
    float rs0 = rsqrtf(sq.x * invN - mu0 * mu0 + BN_EPS);
    float rs1 = rsqrtf(sq.y * invN - mu1 * mu1 + BN_EPS);
    float rs2 = rsqrtf(sq.z * invN - mu2 * mu2 + BN_EPS);
    float rs3 = rsqrtf(sq.w * invN - mu3 * mu3 + BN_EPS);
    float4 g = ((const float4*)gamma)[f4];
    float4 bt = ((const float4*)beta)[f4];
    float4 hv = ((const float4*)h2)[i];
    float4 xv = ((const float4*)x)[i];
    float4 o;
    o.x = (xv.x + gelu_f((hv.x - mu0) * rs0 * g.x + bt.x)) * INV_SQRT2;
    o.y = (xv.y + gelu_f((hv.y - mu1) * rs1 * g.y + bt.y)) * INV_SQRT2;
    o.z = (xv.z + gelu_f((hv.z - mu2) * rs2 * g.z + bt.z)) * INV_SQRT2;
    o.w = (xv.w + gelu_f((hv.w - mu3) * rs3 * g.w + bt.w)) * INV_SQRT2;
    ((float4*)out)[i] = o;
}

// ---------------- launch ----------------
extern "C" void kernel_launch(void* const* d_in, const int* in_sizes, int n_in,
                              void* d_out, int out_size, void* d_ws, size_t ws_size,
                              hipStream_t stream) {
    const float* x = (const float*)d_in[0];
    const int* ei = (const int*)d_in[1];
    const float* attr = (const float*)d_in[2];
    const float* W_be = (const float*)d_in[3];
    const float* b_be = (const float*)d_in[4];
    const float* eps = (const float*)d_in[5];
    const float* W1 = (const float*)d_in[6];
    const float* b1 = (const float*)d_in[7];
    const float* W2 = (const float*)d_in[8];
    const float* b2 = (const float*)d_in[9];
    const float* gamma = (const float*)d_in[10];
    const float* beta = (const float*)d_in[11];
    float* out = (float*)d_out;

    const size_t emb_f32_bytes = (size_t)N_EDGES * DIM * 4;   // 204.8 MB
    const size_t node_bytes = (size_t)N_NODES * DIM * 4;      // 12.8 MB
    const size_t edge_int_bytes = (size_t)N_EDGES * 4;        // 3.2 MB
    const size_t node_int_bytes = ((size_t)(N_NODES + 1) * 4 + 255) & ~(size_t)255;
    // rest = agg + h2 + xA + 2 edge-int + 3 node-int + part + stats
    const size_t rest = 3 * node_bytes + 2 * edge_int_bytes + 3 * node_int_bytes + 4096;
    bool use_f32_emb = (ws_size >= emb_f32_bytes + rest);

    char* ws = (char*)d_ws;
    size_t off = 0;
    auto alloc = [&](size_t bytes) { void* p = ws + off; off += (bytes + 255) & ~(size_t)255; return p; };

    size_t emb_bytes = use_f32_emb ? emb_f32_bytes : (size_t)N_EDGES * DIM * 2;
    void* emb = alloc(emb_bytes);
    float* aggbuf = (float*)alloc(node_bytes);
    float* h2 = (float*)alloc(node_bytes);
    float* xA = (float*)alloc(node_bytes);
    int* src_sorted = (int*)alloc(edge_int_bytes);
    int* pos_of_edge = (int*)alloc(edge_int_bytes);
    int* row_start = (int*)alloc((size_t)(N_NODES + 1) * 4);
    int* cursor = (int*)alloc((size_t)N_NODES * 4);
    int* deg = (int*)alloc((size_t)N_NODES * 4);
    int* part = (int*)alloc(1024);
    float* stats = (float*)alloc(512);

    const int nodeBlocks = (N_NODES + 255) / 256;            // 196
    const int edgeThreadBlocks = (N_EDGES + 255) / 256;      // 3125
    const int beBlocks = (N_EDGES + 63) / 64;                // 12500
    const int nodeVecBlocks = (N_NODES * DIM / 4 + 255) / 256;  // 3125
    const int aggBlocks = (N_NODES + 3) / 4;                 // 12500 (4 waves/block)
    const int mlpBlocks = (N_NODES + 63) / 64;               // 782

    // --- CSR build (independent of features) ---
    zero_kernel<<<nodeBlocks, 256, 0, stream>>>(deg);
    hist_kernel<<<edgeThreadBlocks, 256, 0, stream>>>(ei, deg);
    scan_partials<<<nodeBlocks, 256, 0, stream>>>(deg, part);
    scan_top<<<1, 256, 0, stream>>>(part, nodeBlocks);
    scan_final<<<nodeBlocks, 256, 0, stream>>>(deg, part, row_start, cursor);
    scatter_kernel<<<edgeThreadBlocks, 256, 0, stream>>>(ei, cursor, pos_of_edge, src_sorted);

    // --- bond encoder straight into CSR order ---
    if (use_f32_emb) {
        be_gemm<float><<<beBlocks, 256, 0, stream>>>(attr, W_be, b_be, pos_of_edge, (float*)emb, N_EDGES);
    } else {
        be_gemm<unsigned short><<<beBlocks, 256, 0, stream>>>(attr, W_be, b_be, pos_of_edge, (unsigned short*)emb, N_EDGES);
    }

    for (int l = 0; l < NLAYERS; l++) {
        const float* xin = (l == 0) ? x : ((l == 1) ? xA : out);
        float* xout = (l == 0) ? xA : out;
        if (use_f32_emb) {
            agg_kernel<float><<<aggBlocks, 256, 0, stream>>>(xin, row_start, src_sorted,
                                                             (const float*)emb, eps, l, aggbuf, stats);
        } else {
            agg_kernel<unsigned short><<<aggBlocks, 256, 0, stream>>>(xin, row_start, src_sorted,
                                                                      (const unsigned short*)emb, eps, l, aggbuf, stats);
        }
        mlp_kernel<<<mlpBlocks, 256, 0, stream>>>(aggbuf, W1 + l * 4096, b1 + l * 64,
                                                  W2 + l * 4096, b2 + l * 64, h2, stats);
        bn_kernel<<<nodeVecBlocks, 256, 0, stream>>>(xin, h2, stats, gamma + l * 64,
                                                     beta + l * 64, xout);
    }
}

// Round 4
// 942.334 us; speedup vs baseline: 2.8903x; 1.0282x over previous
//
#include <hip/hip_runtime.h>
#include <hip/hip_bf16.h>
#include <math.h>

#define N_NODES 50000
#define N_EDGES 800000
#define DIM 64
#define NLAYERS 3
#define BN_EPS 1e-5f
#define INV_SQRT2 0.7071067811865475f

// ---------------- helpers ----------------

__device__ __forceinline__ float gelu_f(float v) {
    // exact (erf) GELU, matches torch/jax approximate=False
    return 0.5f * v * (1.0f + erff(v * INV_SQRT2));
}

__device__ __forceinline__ float bf2f(unsigned short u) {
    union { unsigned int i; float f; } t; t.i = ((unsigned int)u) << 16; return t.f;
}
__device__ __forceinline__ unsigned short f2bf(float f) {
    union { float f; unsigned int i; } t; t.f = f;
    unsigned int x = t.i;
    unsigned int r = (x >> 16) & 1u;
    x += 0x7fffu + r;          // round-to-nearest-even
    return (unsigned short)(x >> 16);
}

// ---------------- CSR build ----------------

__global__ __launch_bounds__(256) void zero_kernel(int* __restrict__ deg) {
    int i = blockIdx.x * 256 + threadIdx.x;
    if (i < N_NODES) deg[i] = 0;
}

__global__ __launch_bounds__(256) void hist_kernel(const int* __restrict__ ei,
                                                   int* __restrict__ deg) {
    int e = blockIdx.x * 256 + threadIdx.x;
    if (e < N_EDGES) atomicAdd(&deg[ei[N_EDGES + e]], 1);
}

// per-block sums of deg (blocks of 256)
__global__ __launch_bounds__(256) void scan_partials(const int* __restrict__ deg,
                                                     int* __restrict__ part) {
    __shared__ int red[256];
    int i = blockIdx.x * 256 + threadIdx.x;
    int v = (i < N_NODES) ? deg[i] : 0;
    red[threadIdx.x] = v; __syncthreads();
    for (int s = 128; s > 0; s >>= 1) {
        if (threadIdx.x < s) red[threadIdx.x] += red[threadIdx.x + s];
        __syncthreads();
    }
    if (threadIdx.x == 0) part[blockIdx.x] = red[0];
}

// single block: exclusive scan of nparts (<256) partials in-place
__global__ __launch_bounds__(256) void scan_top(int* __restrict__ part, int nparts) {
    __shared__ int sh[256];
    int v = (threadIdx.x < nparts) ? part[threadIdx.x] : 0;
    sh[threadIdx.x] = v; __syncthreads();
    for (int s = 1; s < 256; s <<= 1) {
        int t = (threadIdx.x >= s) ? sh[threadIdx.x - s] : 0;
        __syncthreads();
        sh[threadIdx.x] += t;
        __syncthreads();
    }
    if (threadIdx.x < nparts) part[threadIdx.x] = sh[threadIdx.x] - v;  // exclusive
}

// final: row_start = exclusive scan; also init cursor
__global__ __launch_bounds__(256) void scan_final(const int* __restrict__ deg,
                                                  const int* __restrict__ part,
                                                  int* __restrict__ row_start,
                                                  int* __restrict__ cursor) {
    __shared__ int sh[256];
    int i = blockIdx.x * 256 + threadIdx.x;
    int v = (i < N_NODES) ? deg[i] : 0;
    sh[threadIdx.x] = v; __syncthreads();
    for (int s = 1; s < 256; s <<= 1) {
        int t = (threadIdx.x >= s) ? sh[threadIdx.x - s] : 0;
        __syncthreads();
        sh[threadIdx.x] += t;
        __syncthreads();
    }
    int excl = sh[threadIdx.x] - v + part[blockIdx.x];
    if (i < N_NODES) { row_start[i] = excl; cursor[i] = excl; }
    if (i == N_NODES - 1) row_start[N_NODES] = excl + v;  // == E
}

__global__ __launch_bounds__(256) void scatter_kernel(const int* __restrict__ ei,
                                                      int* __restrict__ cursor,
                                                      int* __restrict__ edge_of_pos,
                                                      int* __restrict__ src_sorted) {
    int e = blockIdx.x * 256 + threadIdx.x;
    if (e >= N_EDGES) return;
    int d = ei[N_EDGES + e];
    int pos = atomicAdd(&cursor[d], 1);
    edge_of_pos[pos] = e;          // inverse permutation: CSR pos -> edge id
    src_sorted[pos] = ei[e];
}

// ---------------- bond encoder GEMM (CSR-ordered): ----------------
// block handles CSR positions [row0, row0+64): GATHER attr rows via edge_of_pos,
// GEMM in LDS, STREAM bf16 emb store (contiguous).
__global__ __launch_bounds__(256) void be_gemm(const float* __restrict__ attr,
                                               const float* __restrict__ W,
                                               const float* __restrict__ b,
                                               const int* __restrict__ edge_of_pos,
                                               unsigned short* __restrict__ out, int rows) {
    __shared__ float Wl[64][64];    // [k][c]
    __shared__ float tile[64][65];
    __shared__ int eidl[64];
    int tid = threadIdx.x;
    int row0 = blockIdx.x * 64;
    if (tid < 64 && row0 + tid < rows) eidl[tid] = edge_of_pos[row0 + tid];
    for (int i = tid; i < 4096; i += 256) Wl[i >> 6][i & 63] = W[i];
    __syncthreads();
    // gathered tile load: each 64-lane wave-iteration reads one contiguous 256B attr row
    for (int i = tid; i < 4096; i += 256) {
        int r = i >> 6, c = i & 63;
        int gr = row0 + r;
        tile[r][c] = (gr < rows) ? attr[(long long)eidl[r] * DIM + c] : 0.0f;
    }
    __syncthreads();
    int r = tid & 63, c0 = (tid >> 6) * 16;
    float acc[16];
#pragma unroll
    for (int j = 0; j < 16; j++) acc[j] = b[c0 + j];
    for (int k = 0; k < 64; k++) {
        float hv = tile[r][k];
#pragma unroll
        for (int j = 0; j < 16; j++) acc[j] += hv * Wl[k][c0 + j];
    }
    __syncthreads();
#pragma unroll
    for (int j = 0; j < 16; j++) tile[r][c0 + j] = acc[j];
    __syncthreads();
    // streaming bf16 store: contiguous 8KB per block
    for (int i = tid; i < 1024; i += 256) {   // 1024 groups of 4 elements
        int rr = i >> 4, c4 = (i & 15) * 4;
        int gr = row0 + rr;
        if (gr < rows) {
            ushort4 u;
            u.x = f2bf(tile[rr][c4]);
            u.y = f2bf(tile[rr][c4 + 1]);
            u.z = f2bf(tile[rr][c4 + 2]);
            u.w = f2bf(tile[rr][c4 + 3]);
            *(ushort4*)(out + (long long)gr * DIM + c4) = u;
        }
    }
}

// ---------------- aggregation: one wave per node, one lane per feature ----------------
__global__ __launch_bounds__(256) void agg_kernel(const float* __restrict__ x,
                                                  const int* __restrict__ row_start,
                                                  const int* __restrict__ src_sorted,
                                                  const unsigned short* __restrict__ emb,  // bf16, CSR order
                                                  const float* __restrict__ eps, int layer,
                                                  float* __restrict__ hout,
                                                  float* __restrict__ stats) {
    if (blockIdx.x == 0 && threadIdx.x < 128) stats[threadIdx.x] = 0.0f;
    int node = (blockIdx.x * 256 + threadIdx.x) >> 6;
    int lane = threadIdx.x & 63;
    if (node >= N_NODES) return;
    int beg = row_start[node], end = row_start[node + 1];
    float acc = 0.0f;
    int p = beg;
    for (; p + 1 < end; p += 2) {
        int s0 = src_sorted[p];
        int s1 = src_sorted[p + 1];
        float e0 = bf2f(emb[(long long)p * DIM + lane]);
        float e1 = bf2f(emb[(long long)(p + 1) * DIM + lane]);
        float x0 = x[(long long)s0 * DIM + lane];
        float x1 = x[(long long)s1 * DIM + lane];
        acc += gelu_f(x0 + e0);
        acc += gelu_f(x1 + e1);
    }
    if (p < end) {
        int s0 = src_sorted[p];
        float e0 = bf2f(emb[(long long)p * DIM + lane]);
        float x0 = x[(long long)s0 * DIM + lane];
        acc += gelu_f(x0 + e0);
    }
    float e1f = 1.0f + eps[layer];
    hout[(long long)node * DIM + lane] = e1f * x[(long long)node * DIM + lane] + acc;
}

// ---------------- per-node MLP + BN-stat accumulation ----------------
__global__ __launch_bounds__(256) void mlp_kernel(const float* __restrict__ h_in,
                                                  const float* __restrict__ W1,
                                                  const float* __restrict__ b1,
                                                  const float* __restrict__ W2,
                                                  const float* __restrict__ b2,
                                                  float* __restrict__ h2,
                                                  float* __restrict__ stats) {
    __shared__ float W1l[64][64];
    __shared__ float W2l[64][64];
    __shared__ float tileA[64][65];
    __shared__ float tileB[64][65];
    __shared__ float sred[4][64];
    __shared__ float sred2[4][64];
    int tid = threadIdx.x;
    for (int i = tid; i < 4096; i += 256) {
        W1l[i >> 6][i & 63] = W1[i];
        W2l[i >> 6][i & 63] = W2[i];
    }
    int row0 = blockIdx.x * 64;
    for (int i = tid; i < 4096; i += 256) {
        int r = i >> 6, c = i & 63;
        int gr = row0 + r;
        tileA[r][c] = (gr < N_NODES) ? h_in[(long long)gr * DIM + c] : 0.0f;
    }
    __syncthreads();
    int r = tid & 63, q = tid >> 6, c0 = q * 16;
    float acc[16];
#pragma unroll
    for (int j = 0; j < 16; j++) acc[j] = b1[c0 + j];
    for (int k = 0; k < 64; k++) {
        float hv = tileA[r][k];
#pragma unroll
        for (int j = 0; j < 16; j++) acc[j] += hv * W1l[k][c0 + j];
    }
#pragma unroll
    for (int j = 0; j < 16; j++) tileB[r][c0 + j] = gelu_f(acc[j]);
    __syncthreads();
#pragma unroll
    for (int j = 0; j < 16; j++) acc[j] = b2[c0 + j];
    for (int k = 0; k < 64; k++) {
        float hv = tileB[r][k];
#pragma unroll
        for (int j = 0; j < 16; j++) acc[j] += hv * W2l[k][c0 + j];
    }
    __syncthreads();
#pragma unroll
    for (int j = 0; j < 16; j++) tileA[r][c0 + j] = acc[j];
    __syncthreads();
    int nvalid = min(64, N_NODES - row0);
    // coalesced write-out
    for (int i = tid; i < 1024; i += 256) {
        int rr = i >> 4, c4 = (i & 15) * 4;
        int gr = row0 + rr;
        if (gr < N_NODES) {
            float4 v = make_float4(tileA[rr][c4], tileA[rr][c4 + 1], tileA[rr][c4 + 2], tileA[rr][c4 + 3]);
            *(float4*)(h2 + (long long)gr * DIM + c4) = v;
        }
    }
    // BN partial stats: feature f = tid&63, quarter q sums 16 rows
    float s = 0.0f, s2 = 0.0f;
    int f = tid & 63;
    int rend = min(q * 16 + 16, nvalid);
    for (int rr = q * 16; rr < rend; rr++) {
        float v = tileA[rr][f];
        s += v; s2 += v * v;
    }
    sred[q][f] = s; sred2[q][f] = s2;
    __syncthreads();
    if (tid < 64) {
        float ts = sred[0][tid] + sred[1][tid] + sred[2][tid] + sred[3][tid];
        float ts2 = sred2[0][tid] + sred2[1][tid] + sred2[2][tid] + sred2[3][tid];
        unsafeAtomicAdd(&stats[tid], ts);
        unsafeAtomicAdd(&stats[64 + tid], ts2);
    }
}

// ---------------- BN + GELU + residual ----------------
__global__ __launch_bounds__(256) void bn_kernel(const float* __restrict__ x,
                                                 const float* __restrict__ h2,
                                                 const float* __restrict__ stats,
                                                 const float* __restrict__ gamma,
                                                 const float* __restrict__ beta,
                                                 float* __restrict__ out) {
    int i = blockIdx.x * 256 + threadIdx.x;
    if (i >= N_NODES * DIM / 4) return;
    int f4 = i & 15;   // feature group (4 features)
    float4 sum = ((const float4*)stats)[f4];
    float4 sq = ((const float4*)(stats + 64))[f4];
    const float invN = 1.0f / (float)N_NODES;
    float mu0 = sum.x * invN, mu1 = sum.y * invN, mu2 = sum.z * invN, mu3 = sum.w * invN;
    float rs0 = rsqrtf(sq.x * invN - mu0 * mu0 + BN_EPS);
    float rs1 = rsqrtf(sq.y * invN - mu1 * mu1 + BN_EPS);
    float rs2 = rsqrtf(sq.z * invN - mu2 * mu2 + BN_EPS);
    float rs3 = rsqrtf(sq.w * invN - mu3 * mu3 + BN_EPS);
    float4 g = ((const float4*)gamma)[f4];
    float4 bt = ((const float4*)beta)[f4];
    float4 hv = ((const float4*)h2)[i];
    float4 xv = ((const float4*)x)[i];
    float4 o;
    o.x = (xv.x + gelu_f((hv.x - mu0) * rs0 * g.x + bt.x)) * INV_SQRT2;
    o.y = (xv.y + gelu_f((hv.y - mu1) * rs1 * g.y + bt.y)) * INV_SQRT2;
    o.z = (xv.z + gelu_f((hv.z - mu2) * rs2 * g.z + bt.z)) * INV_SQRT2;
    o.w = (xv.w + gelu_f((hv.w - mu3) * rs3 * g.w + bt.w)) * INV_SQRT2;
    ((float4*)out)[i] = o;
}

// ---------------- launch ----------------
extern "C" void kernel_launch(void* const* d_in, const int* in_sizes, int n_in,
                              void* d_out, int out_size, void* d_ws, size_t ws_size,
                              hipStream_t stream) {
    const float* x = (const float*)d_in[0];
    const int* ei = (const int*)d_in[1];
    const float* attr = (const float*)d_in[2];
    const float* W_be = (const float*)d_in[3];
    const float* b_be = (const float*)d_in[4];
    const float* eps = (const float*)d_in[5];
    const float* W1 = (const float*)d_in[6];
    const float* b1 = (const float*)d_in[7];
    const float* W2 = (const float*)d_in[8];
    const float* b2 = (const float*)d_in[9];
    const float* gamma = (const float*)d_in[10];
    const float* beta = (const float*)d_in[11];
    float* out = (float*)d_out;

    const size_t emb_bytes = (size_t)N_EDGES * DIM * 2;       // 102.4 MB (bf16)
    const size_t node_bytes = (size_t)N_NODES * DIM * 4;      // 12.8 MB
    const size_t edge_int_bytes = (size_t)N_EDGES * 4;        // 3.2 MB

    char* ws = (char*)d_ws;
    size_t off = 0;
    auto alloc = [&](size_t bytes) { void* p = ws + off; off += (bytes + 255) & ~(size_t)255; return p; };

    unsigned short* emb = (unsigned short*)alloc(emb_bytes);
    float* aggbuf = (float*)alloc(node_bytes);
    float* h2 = (float*)alloc(node_bytes);
    float* xA = (float*)alloc(node_bytes);
    int* src_sorted = (int*)alloc(edge_int_bytes);
    int* edge_of_pos = (int*)alloc(edge_int_bytes);
    int* row_start = (int*)alloc((size_t)(N_NODES + 1) * 4);
    int* cursor = (int*)alloc((size_t)N_NODES * 4);
    int* deg = (int*)alloc((size_t)N_NODES * 4);
    int* part = (int*)alloc(1024);
    float* stats = (float*)alloc(512);

    const int nodeBlocks = (N_NODES + 255) / 256;            // 196
    const int edgeThreadBlocks = (N_EDGES + 255) / 256;      // 3125
    const int beBlocks = (N_EDGES + 63) / 64;                // 12500
    const int nodeVecBlocks = (N_NODES * DIM / 4 + 255) / 256;  // 3125
    const int aggBlocks = (N_NODES + 3) / 4;                 // 12500 (4 waves/block)
    const int mlpBlocks = (N_NODES + 63) / 64;               // 782

    // --- CSR build (independent of features) ---
    zero_kernel<<<nodeBlocks, 256, 0, stream>>>(deg);
    hist_kernel<<<edgeThreadBlocks, 256, 0, stream>>>(ei, deg);
    scan_partials<<<nodeBlocks, 256, 0, stream>>>(deg, part);
    scan_top<<<1, 256, 0, stream>>>(part, nodeBlocks);
    scan_final<<<nodeBlocks, 256, 0, stream>>>(deg, part, row_start, cursor);
    scatter_kernel<<<edgeThreadBlocks, 256, 0, stream>>>(ei, cursor, edge_of_pos, src_sorted);

    // --- bond encoder: gather attr in CSR order, stream bf16 emb out ---
    be_gemm<<<beBlocks, 256, 0, stream>>>(attr, W_be, b_be, edge_of_pos, emb, N_EDGES);

    for (int l = 0; l < NLAYERS; l++) {
        const float* xin = (l == 0) ? x : ((l == 1) ? xA : out);
        float* xout = (l == 0) ? xA : out;
        agg_kernel<<<aggBlocks, 256, 0, stream>>>(xin, row_start, src_sorted,
                                                  emb, eps, l, aggbuf, stats);
        mlp_kernel<<<mlpBlocks, 256, 0, stream>>>(aggbuf, W1 + l * 4096, b1 + l * 64,
                                                  W2 + l * 4096, b2 + l * 64, h2, stats);
        bn_kernel<<<nodeVecBlocks, 256, 0, stream>>>(xin, h2, stats, gamma + l * 64,
                                                     beta + l * 64, xout);
    }
}

// Round 5
// 763.115 us; speedup vs baseline: 3.5691x; 1.2349x over previous
//
#include <hip/hip_runtime.h>
#include <hip/hip_bf16.h>
#include <math.h>

#define N_NODES 50000
#define N_EDGES 800000
#define DIM 64
#define NLAYERS 3
#define BN_EPS 1e-5f
#define INV_SQRT2 0.7071067811865475f

// ---------------- helpers ----------------

__device__ __forceinline__ float gelu_f(float v) {
    return 0.5f * v * (1.0f + erff(v * INV_SQRT2));  // exact erf GELU
}

__device__ __forceinline__ float bf2f(unsigned short u) {
    union { unsigned int i; float f; } t; t.i = ((unsigned int)u) << 16; return t.f;
}
__device__ __forceinline__ unsigned short f2bf(float f) {
    union { float f; unsigned int i; } t; t.f = f;
    unsigned int x = t.i;
    unsigned int r = (x >> 16) & 1u;
    x += 0x7fffu + r;          // round-to-nearest-even
    return (unsigned short)(x >> 16);
}

// ---------------- CSR build ----------------

__global__ __launch_bounds__(256) void zero_kernel(int* __restrict__ deg) {
    int i = blockIdx.x * 256 + threadIdx.x;
    if (i < N_NODES) deg[i] = 0;
}

__global__ __launch_bounds__(256) void hist_kernel(const int* __restrict__ ei,
                                                   int* __restrict__ deg) {
    int e = blockIdx.x * 256 + threadIdx.x;
    if (e < N_EDGES) atomicAdd(&deg[ei[N_EDGES + e]], 1);
}

__global__ __launch_bounds__(256) void scan_partials(const int* __restrict__ deg,
                                                     int* __restrict__ part) {
    __shared__ int red[256];
    int i = blockIdx.x * 256 + threadIdx.x;
    int v = (i < N_NODES) ? deg[i] : 0;
    red[threadIdx.x] = v; __syncthreads();
    for (int s = 128; s > 0; s >>= 1) {
        if (threadIdx.x < s) red[threadIdx.x] += red[threadIdx.x + s];
        __syncthreads();
    }
    if (threadIdx.x == 0) part[blockIdx.x] = red[0];
}

__global__ __launch_bounds__(256) void scan_top(int* __restrict__ part, int nparts) {
    __shared__ int sh[256];
    int v = (threadIdx.x < nparts) ? part[threadIdx.x] : 0;
    sh[threadIdx.x] = v; __syncthreads();
    for (int s = 1; s < 256; s <<= 1) {
        int t = (threadIdx.x >= s) ? sh[threadIdx.x - s] : 0;
        __syncthreads();
        sh[threadIdx.x] += t;
        __syncthreads();
    }
    if (threadIdx.x < nparts) part[threadIdx.x] = sh[threadIdx.x] - v;  // exclusive
}

__global__ __launch_bounds__(256) void scan_final(const int* __restrict__ deg,
                                                  const int* __restrict__ part,
                                                  int* __restrict__ row_start,
                                                  int* __restrict__ cursor) {
    __shared__ int sh[256];
    int i = blockIdx.x * 256 + threadIdx.x;
    int v = (i < N_NODES) ? deg[i] : 0;
    sh[threadIdx.x] = v; __syncthreads();
    for (int s = 1; s < 256; s <<= 1) {
        int t = (threadIdx.x >= s) ? sh[threadIdx.x - s] : 0;
        __syncthreads();
        sh[threadIdx.x] += t;
        __syncthreads();
    }
    int excl = sh[threadIdx.x] - v + part[blockIdx.x];
    if (i < N_NODES) { row_start[i] = excl; cursor[i] = excl; }
    if (i == N_NODES - 1) row_start[N_NODES] = excl + v;  // == E
}

__global__ __launch_bounds__(256) void scatter_kernel(const int* __restrict__ ei,
                                                      int* __restrict__ cursor,
                                                      int* __restrict__ edge_of_pos,
                                                      int* __restrict__ src_sorted) {
    int e = blockIdx.x * 256 + threadIdx.x;
    if (e >= N_EDGES) return;
    int d = ei[N_EDGES + e];
    int pos = atomicAdd(&cursor[d], 1);
    edge_of_pos[pos] = e;
    src_sorted[pos] = ei[e];
}

// ---------------- bond encoder GEMM (CSR-ordered, register-blocked) ----------------
// 128 CSR rows per block, 256 threads; thread computes 8 rows x 4 cols.
// A staged transposed [k][r] so both operands are ds_read_b128.
__global__ __launch_bounds__(256) void be_gemm(const float* __restrict__ attr,
                                               const float* __restrict__ W,
                                               const float* __restrict__ b,
                                               const int* __restrict__ edge_of_pos,
                                               unsigned short* __restrict__ out, int rows) {
    __shared__ float Wl[64][68];    // [k][c]
    __shared__ float At[64][132];   // [k][r], 128 rows + pad (stride%8==4 -> write conflicts ~8-way only)
    __shared__ int eidl[128];
    int tid = threadIdx.x;
    int row0 = blockIdx.x * 128;
    if (tid < 128) {
        int gr = row0 + tid;
        eidl[tid] = (gr < rows) ? edge_of_pos[gr] : 0;
    }
    {
        const float4* W4 = (const float4*)W;
        for (int i = tid; i < 1024; i += 256) {
            int r = i >> 4, cq = i & 15;
            float4 v = W4[i];
            *(float4*)&Wl[r][cq * 4] = v;
        }
    }
    __syncthreads();
    {   // gathered load (256B/row segments) + transpose into At
        const float4* attr4 = (const float4*)attr;
        for (int i = tid; i < 2048; i += 256) {
            int r = i >> 4, cq = i & 15;
            int gr = row0 + r;
            float4 v = make_float4(0.f, 0.f, 0.f, 0.f);
            if (gr < rows) v = attr4[(long long)eidl[r] * 16 + cq];
            int c = cq * 4;
            At[c][r] = v.x; At[c + 1][r] = v.y; At[c + 2][r] = v.z; At[c + 3][r] = v.w;
        }
    }
    __syncthreads();
    int cg = tid & 15, rg = tid >> 4;
    int c0 = cg * 4, r0 = rg * 8;
    float acc[8][4];
    float4 bv = *(const float4*)&b[c0];
#pragma unroll
    for (int ri = 0; ri < 8; ri++) {
        acc[ri][0] = bv.x; acc[ri][1] = bv.y; acc[ri][2] = bv.z; acc[ri][3] = bv.w;
    }
    for (int k = 0; k < 64; k++) {
        float4 w = *(float4*)&Wl[k][c0];
        float4 a0 = *(float4*)&At[k][r0];
        float4 a1 = *(float4*)&At[k][r0 + 4];
        float av[8] = {a0.x, a0.y, a0.z, a0.w, a1.x, a1.y, a1.z, a1.w};
#pragma unroll
        for (int ri = 0; ri < 8; ri++) {
            acc[ri][0] += av[ri] * w.x;
            acc[ri][1] += av[ri] * w.y;
            acc[ri][2] += av[ri] * w.z;
            acc[ri][3] += av[ri] * w.w;
        }
    }
    // direct bf16 store: 16 threads x 8B = 128B contiguous per row
#pragma unroll
    for (int ri = 0; ri < 8; ri++) {
        int row = row0 + r0 + ri;
        if (row < rows) {
            ushort4 u;
            u.x = f2bf(acc[ri][0]); u.y = f2bf(acc[ri][1]);
            u.z = f2bf(acc[ri][2]); u.w = f2bf(acc[ri][3]);
            *(ushort4*)(out + (long long)row * DIM + c0) = u;
        }
    }
}

// ---------------- aggregation: wave per node, lane = (feature-quad, edge-slot) ----------------
__global__ __launch_bounds__(256) void agg_kernel(const float* __restrict__ x,
                                                  const int* __restrict__ row_start,
                                                  const int* __restrict__ src_sorted,
                                                  const unsigned short* __restrict__ emb,  // bf16 CSR order
                                                  const float* __restrict__ eps, int layer,
                                                  float* __restrict__ hout,
                                                  float* __restrict__ stats) {
    if (blockIdx.x == 0 && threadIdx.x < 128) stats[threadIdx.x] = 0.0f;
    int node = (blockIdx.x * 256 + threadIdx.x) >> 6;
    int lane = threadIdx.x & 63;
    if (node >= N_NODES) return;
    int fq = lane & 15;       // feature quad: features 4*fq .. 4*fq+3
    int eq = lane >> 4;       // edge slot 0..3
    int beg = row_start[node], end = row_start[node + 1];
    const ushort4* emb4 = (const ushort4*)emb;
    const float4* x4 = (const float4*)x;
    float4 acc = make_float4(0.f, 0.f, 0.f, 0.f);
    for (int p0 = beg; p0 < end; p0 += 4) {
        int p = p0 + eq;
        bool valid = (p < end);
        int pc = valid ? p : (end - 1);
        int s = src_sorted[pc];
        ushort4 ev = emb4[(long long)pc * 16 + fq];   // 4 rows -> 512B contiguous per wave
        float4 xv = x4[(long long)s * 16 + fq];
        float m0 = gelu_f(xv.x + bf2f(ev.x));
        float m1 = gelu_f(xv.y + bf2f(ev.y));
        float m2 = gelu_f(xv.z + bf2f(ev.z));
        float m3 = gelu_f(xv.w + bf2f(ev.w));
        if (valid) { acc.x += m0; acc.y += m1; acc.z += m2; acc.w += m3; }
    }
    // butterfly over edge slots
    acc.x += __shfl_xor(acc.x, 16, 64); acc.y += __shfl_xor(acc.y, 16, 64);
    acc.z += __shfl_xor(acc.z, 16, 64); acc.w += __shfl_xor(acc.w, 16, 64);
    acc.x += __shfl_xor(acc.x, 32, 64); acc.y += __shfl_xor(acc.y, 32, 64);
    acc.z += __shfl_xor(acc.z, 32, 64); acc.w += __shfl_xor(acc.w, 32, 64);
    if (eq == 0) {
        float e1f = 1.0f + eps[layer];
        float4 xv = x4[(long long)node * 16 + fq];
        float4 o;
        o.x = e1f * xv.x + acc.x; o.y = e1f * xv.y + acc.y;
        o.z = e1f * xv.z + acc.z; o.w = e1f * xv.w + acc.w;
        ((float4*)hout)[(long long)node * 16 + fq] = o;
    }
}

// ---------------- per-node MLP (register-blocked, 2 GEMMs) + BN stats ----------------
__global__ __launch_bounds__(256) void mlp_kernel(const float* __restrict__ h_in,
                                                  const float* __restrict__ W1,
                                                  const float* __restrict__ b1,
                                                  const float* __restrict__ W2,
                                                  const float* __restrict__ b2,
                                                  float* __restrict__ h2,
                                                  float* __restrict__ stats) {
    __shared__ float W1l[64][68];
    __shared__ float W2l[64][68];
    __shared__ float T[64][68];     // transposed [k][r]; reused for mid activation
    __shared__ float sredS[4][64];
    __shared__ float sredQ[4][64];
    int tid = threadIdx.x;
    int row0 = blockIdx.x * 64;
    {
        const float4* W14 = (const float4*)W1;
        const float4* W24 = (const float4*)W2;
        const float4* h4 = (const float4*)h_in;
        for (int i = tid; i < 1024; i += 256) {
            int r = i >> 4, cq = i & 15;
            *(float4*)&W1l[r][cq * 4] = W14[i];
            *(float4*)&W2l[r][cq * 4] = W24[i];
            int gr = row0 + r;
            float4 v = make_float4(0.f, 0.f, 0.f, 0.f);
            if (gr < N_NODES) v = h4[(long long)gr * 16 + cq];
            int c = cq * 4;
            T[c][r] = v.x; T[c + 1][r] = v.y; T[c + 2][r] = v.z; T[c + 3][r] = v.w;
        }
    }
    __syncthreads();
    int cg = tid & 15, rg = tid >> 4;
    int c0 = cg * 4, r0 = rg * 4;
    float acc[4][4];
    {
        float4 bv = *(const float4*)&b1[c0];
#pragma unroll
        for (int ri = 0; ri < 4; ri++) {
            acc[ri][0] = bv.x; acc[ri][1] = bv.y; acc[ri][2] = bv.z; acc[ri][3] = bv.w;
        }
    }
    for (int k = 0; k < 64; k++) {
        float4 a = *(float4*)&T[k][r0];
        float4 w = *(float4*)&W1l[k][c0];
        float av[4] = {a.x, a.y, a.z, a.w};
#pragma unroll
        for (int ri = 0; ri < 4; ri++) {
            acc[ri][0] += av[ri] * w.x;
            acc[ri][1] += av[ri] * w.y;
            acc[ri][2] += av[ri] * w.z;
            acc[ri][3] += av[ri] * w.w;
        }
    }
    __syncthreads();   // everyone done reading T
    // write gelu(acc) transposed into T: T[c][r]
#pragma unroll
    for (int ci = 0; ci < 4; ci++) {
        float4 m;
        m.x = gelu_f(acc[0][ci]); m.y = gelu_f(acc[1][ci]);
        m.z = gelu_f(acc[2][ci]); m.w = gelu_f(acc[3][ci]);
        *(float4*)&T[c0 + ci][r0] = m;
    }
    __syncthreads();
    float acc2[4][4];
    {
        float4 bv = *(const float4*)&b2[c0];
#pragma unroll
        for (int ri = 0; ri < 4; ri++) {
            acc2[ri][0] = bv.x; acc2[ri][1] = bv.y; acc2[ri][2] = bv.z; acc2[ri][3] = bv.w;
        }
    }
    for (int k = 0; k < 64; k++) {
        float4 a = *(float4*)&T[k][r0];
        float4 w = *(float4*)&W2l[k][c0];
        float av[4] = {a.x, a.y, a.z, a.w};
#pragma unroll
        for (int ri = 0; ri < 4; ri++) {
            acc2[ri][0] += av[ri] * w.x;
            acc2[ri][1] += av[ri] * w.y;
            acc2[ri][2] += av[ri] * w.z;
            acc2[ri][3] += av[ri] * w.w;
        }
    }
    // global store + per-thread BN partials
    float4 s = make_float4(0.f, 0.f, 0.f, 0.f);
    float4 q = make_float4(0.f, 0.f, 0.f, 0.f);
#pragma unroll
    for (int ri = 0; ri < 4; ri++) {
        int row = row0 + r0 + ri;
        if (row < N_NODES) {
            float4 o = make_float4(acc2[ri][0], acc2[ri][1], acc2[ri][2], acc2[ri][3]);
            *(float4*)(h2 + (long long)row * DIM + c0) = o;
            s.x += o.x; s.y += o.y; s.z += o.z; s.w += o.w;
            q.x += o.x * o.x; q.y += o.y * o.y; q.z += o.z * o.z; q.w += o.w * o.w;
        }
    }
    // reduce over the wave's 4 row-groups
    s.x += __shfl_xor(s.x, 16, 64); s.y += __shfl_xor(s.y, 16, 64);
    s.z += __shfl_xor(s.z, 16, 64); s.w += __shfl_xor(s.w, 16, 64);
    q.x += __shfl_xor(q.x, 16, 64); q.y += __shfl_xor(q.y, 16, 64);
    q.z += __shfl_xor(q.z, 16, 64); q.w += __shfl_xor(q.w, 16, 64);
    s.x += __shfl_xor(s.x, 32, 64); s.y += __shfl_xor(s.y, 32, 64);
    s.z += __shfl_xor(s.z, 32, 64); s.w += __shfl_xor(s.w, 32, 64);
    q.x += __shfl_xor(q.x, 32, 64); q.y += __shfl_xor(q.y, 32, 64);
    q.z += __shfl_xor(q.z, 32, 64); q.w += __shfl_xor(q.w, 32, 64);
    int wv = tid >> 6;
    if ((tid & 63) < 16) {
        *(float4*)&sredS[wv][c0] = s;
        *(float4*)&sredQ[wv][c0] = q;
    }
    __syncthreads();
    if (tid < 64) {
        float ts = sredS[0][tid] + sredS[1][tid] + sredS[2][tid] + sredS[3][tid];
        float tq = sredQ[0][tid] + sredQ[1][tid] + sredQ[2][tid] + sredQ[3][tid];
        unsafeAtomicAdd(&stats[tid], ts);
        unsafeAtomicAdd(&stats[64 + tid], tq);
    }
}

// ---------------- BN + GELU + residual ----------------
__global__ __launch_bounds__(256) void bn_kernel(const float* __restrict__ x,
                                                 const float* __restrict__ h2,
                                                 const float* __restrict__ stats,
                                                 const float* __restrict__ gamma,
                                                 const float* __restrict__ beta,
                                                 float* __restrict__ out) {
    int i = blockIdx.x * 256 + threadIdx.x;
    if (i >= N_NODES * DIM / 4) return;
    int f4 = i & 15;
    float4 sum = ((const float4*)stats)[f4];
    float4 sq = ((const float4*)(stats + 64))[f4];
    const float invN = 1.0f / (float)N_NODES;
    float mu0 = sum.x * invN, mu1 = sum.y * invN, mu2 = sum.z * invN, mu3 = sum.w * invN;
    float rs0 = rsqrtf(sq.x * invN - mu0 * mu0 + BN_EPS);
    float rs1 = rsqrtf(sq.y * invN - mu1 * mu1 + BN_EPS);
    float rs2 = rsqrtf(sq.z * invN - mu2 * mu2 + BN_EPS);
    float rs3 = rsqrtf(sq.w * invN - mu3 * mu3 + BN_EPS);
    float4 g = ((const float4*)gamma)[f4];
    float4 bt = ((const float4*)beta)[f4];
    float4 hv = ((const float4*)h2)[i];
    float4 xv = ((const float4*)x)[i];
    float4 o;
    o.x = (xv.x + gelu_f((hv.x - mu0) * rs0 * g.x + bt.x)) * INV_SQRT2;
    o.y = (xv.y + gelu_f((hv.y - mu1) * rs1 * g.y + bt.y)) * INV_SQRT2;
    o.z = (xv.z + gelu_f((hv.z - mu2) * rs2 * g.z + bt.z)) * INV_SQRT2;
    o.w = (xv.w + gelu_f((hv.w - mu3) * rs3 * g.w + bt.w)) * INV_SQRT2;
    ((float4*)out)[i] = o;
}

// ---------------- launch ----------------
extern "C" void kernel_launch(void* const* d_in, const int* in_sizes, int n_in,
                              void* d_out, int out_size, void* d_ws, size_t ws_size,
                              hipStream_t stream) {
    const float* x = (const float*)d_in[0];
    const int* ei = (const int*)d_in[1];
    const float* attr = (const float*)d_in[2];
    const float* W_be = (const float*)d_in[3];
    const float* b_be = (const float*)d_in[4];
    const float* eps = (const float*)d_in[5];
    const float* W1 = (const float*)d_in[6];
    const float* b1 = (const float*)d_in[7];
    const float* W2 = (const float*)d_in[8];
    const float* b2 = (const float*)d_in[9];
    const float* gamma = (const float*)d_in[10];
    const float* beta = (const float*)d_in[11];
    float* out = (float*)d_out;

    const size_t emb_bytes = (size_t)N_EDGES * DIM * 2;       // 102.4 MB (bf16)
    const size_t node_bytes = (size_t)N_NODES * DIM * 4;      // 12.8 MB
    const size_t edge_int_bytes = (size_t)N_EDGES * 4;        // 3.2 MB

    char* ws = (char*)d_ws;
    size_t off = 0;
    auto alloc = [&](size_t bytes) { void* p = ws + off; off += (bytes + 255) & ~(size_t)255; return p; };

    unsigned short* emb = (unsigned short*)alloc(emb_bytes);
    float* aggbuf = (float*)alloc(node_bytes);
    float* h2 = (float*)alloc(node_bytes);
    float* xA = (float*)alloc(node_bytes);
    int* src_sorted = (int*)alloc(edge_int_bytes);
    int* edge_of_pos = (int*)alloc(edge_int_bytes);
    int* row_start = (int*)alloc((size_t)(N_NODES + 1) * 4);
    int* cursor = (int*)alloc((size_t)N_NODES * 4);
    int* deg = (int*)alloc((size_t)N_NODES * 4);
    int* part = (int*)alloc(1024);
    float* stats = (float*)alloc(512);

    const int nodeBlocks = (N_NODES + 255) / 256;            // 196
    const int edgeThreadBlocks = (N_EDGES + 255) / 256;      // 3125
    const int beBlocks = (N_EDGES + 127) / 128;              // 6250
    const int nodeVecBlocks = (N_NODES * DIM / 4 + 255) / 256;  // 3125
    const int aggBlocks = (N_NODES + 3) / 4;                 // 12500 (4 waves/block)
    const int mlpBlocks = (N_NODES + 63) / 64;               // 782

    // --- CSR build ---
    zero_kernel<<<nodeBlocks, 256, 0, stream>>>(deg);
    hist_kernel<<<edgeThreadBlocks, 256, 0, stream>>>(ei, deg);
    scan_partials<<<nodeBlocks, 256, 0, stream>>>(deg, part);
    scan_top<<<1, 256, 0, stream>>>(part, nodeBlocks);
    scan_final<<<nodeBlocks, 256, 0, stream>>>(deg, part, row_start, cursor);
    scatter_kernel<<<edgeThreadBlocks, 256, 0, stream>>>(ei, cursor, edge_of_pos, src_sorted);

    // --- bond encoder: gather attr in CSR order, stream bf16 emb ---
    be_gemm<<<beBlocks, 256, 0, stream>>>(attr, W_be, b_be, edge_of_pos, emb, N_EDGES);

    for (int l = 0; l < NLAYERS; l++) {
        const float* xin = (l == 0) ? x : ((l == 1) ? xA : out);
        float* xout = (l == 0) ? xA : out;
        agg_kernel<<<aggBlocks, 256, 0, stream>>>(xin, row_start, src_sorted,
                                                  emb, eps, l, aggbuf, stats);
        mlp_kernel<<<mlpBlocks, 256, 0, stream>>>(aggbuf, W1 + l * 4096, b1 + l * 64,
                                                  W2 + l * 4096, b2 + l * 64, h2, stats);
        bn_kernel<<<nodeVecBlocks, 256, 0, stream>>>(xin, h2, stats, gamma + l * 64,
                                                     beta + l * 64, xout);
    }
}

// Round 6
// 747.999 us; speedup vs baseline: 3.6413x; 1.0202x over previous
//
#include <hip/hip_runtime.h>
#include <hip/hip_bf16.h>
#include <math.h>

#define N_NODES 50000
#define N_EDGES 800000
#define DIM 64
#define NLAYERS 3
#define BN_EPS 1e-5f
#define INV_SQRT2 0.7071067811865475f

using f32x4 = __attribute__((ext_vector_type(4))) float;
using s16x8 = __attribute__((ext_vector_type(8))) short;

// ---------------- helpers ----------------

__device__ __forceinline__ float gelu_f(float v) {
    return 0.5f * v * (1.0f + erff(v * INV_SQRT2));  // exact erf GELU
}

__device__ __forceinline__ float bf2f(unsigned short u) {
    union { unsigned int i; float f; } t; t.i = ((unsigned int)u) << 16; return t.f;
}
__device__ __forceinline__ unsigned short f2bf(float f) {
    union { float f; unsigned int i; } t; t.f = f;
    unsigned int x = t.i;
    unsigned int r = (x >> 16) & 1u;
    x += 0x7fffu + r;          // round-to-nearest-even
    return (unsigned short)(x >> 16);
}

// ---------------- CSR build ----------------

__global__ __launch_bounds__(256) void zero_kernel(int* __restrict__ deg) {
    int i = blockIdx.x * 256 + threadIdx.x;
    if (i < N_NODES) deg[i] = 0;
}

__global__ __launch_bounds__(256) void hist_kernel(const int* __restrict__ ei,
                                                   int* __restrict__ deg) {
    int e = blockIdx.x * 256 + threadIdx.x;
    if (e < N_EDGES) atomicAdd(&deg[ei[N_EDGES + e]], 1);
}

__global__ __launch_bounds__(256) void scan_partials(const int* __restrict__ deg,
                                                     int* __restrict__ part) {
    __shared__ int red[256];
    int i = blockIdx.x * 256 + threadIdx.x;
    int v = (i < N_NODES) ? deg[i] : 0;
    red[threadIdx.x] = v; __syncthreads();
    for (int s = 128; s > 0; s >>= 1) {
        if (threadIdx.x < s) red[threadIdx.x] += red[threadIdx.x + s];
        __syncthreads();
    }
    if (threadIdx.x == 0) part[blockIdx.x] = red[0];
}

__global__ __launch_bounds__(256) void scan_top(int* __restrict__ part, int nparts) {
    __shared__ int sh[256];
    int v = (threadIdx.x < nparts) ? part[threadIdx.x] : 0;
    sh[threadIdx.x] = v; __syncthreads();
    for (int s = 1; s < 256; s <<= 1) {
        int t = (threadIdx.x >= s) ? sh[threadIdx.x - s] : 0;
        __syncthreads();
        sh[threadIdx.x] += t;
        __syncthreads();
    }
    if (threadIdx.x < nparts) part[threadIdx.x] = sh[threadIdx.x] - v;  // exclusive
}

__global__ __launch_bounds__(256) void scan_final(const int* __restrict__ deg,
                                                  const int* __restrict__ part,
                                                  int* __restrict__ row_start,
                                                  int* __restrict__ cursor) {
    __shared__ int sh[256];
    int i = blockIdx.x * 256 + threadIdx.x;
    int v = (i < N_NODES) ? deg[i] : 0;
    sh[threadIdx.x] = v; __syncthreads();
    for (int s = 1; s < 256; s <<= 1) {
        int t = (threadIdx.x >= s) ? sh[threadIdx.x - s] : 0;
        __syncthreads();
        sh[threadIdx.x] += t;
        __syncthreads();
    }
    int excl = sh[threadIdx.x] - v + part[blockIdx.x];
    if (i < N_NODES) { row_start[i] = excl; cursor[i] = excl; }
    if (i == N_NODES - 1) row_start[N_NODES] = excl + v;  // == E
}

__global__ __launch_bounds__(256) void scatter_kernel(const int* __restrict__ ei,
                                                      int* __restrict__ cursor,
                                                      int* __restrict__ edge_of_pos,
                                                      int* __restrict__ src_sorted) {
    int e = blockIdx.x * 256 + threadIdx.x;
    if (e >= N_EDGES) return;
    int d = ei[N_EDGES + e];
    int pos = atomicAdd(&cursor[d], 1);
    edge_of_pos[pos] = e;
    src_sorted[pos] = ei[e];
}

// ---------------- bond encoder GEMM: MFMA bf16, CSR-ordered output ----------------
// 128 CSR rows/block, 256 thr (4 waves). Wave w computes rows [w*32, w*32+32) x all 64 cols.
// A and W staged in LDS in MFMA fragment order (bf16):
//   element (m,k): lane=(m&15)+16*((k%16)>>2), j=(k&3)+4*((k>>4)&1), kstep=k>>5
//   (16x16x32 bf16 A/B layout: k = 4*(lane>>4) + (j&3) + 16*(j>>2); C/D: col=lane&15, row=4*(lane>>4)+reg)
__global__ __launch_bounds__(256) void be_gemm(const float* __restrict__ attr,
                                               const float* __restrict__ W,
                                               const float* __restrict__ b,
                                               const int* __restrict__ edge_of_pos,
                                               unsigned short* __restrict__ out) {
    __shared__ unsigned short fragA[16][64][8];  // [mtile*2+kstep][lane][j]   16 KB
    __shared__ unsigned short fragB[8][64][8];   // [ntile*2+kstep][lane][j]    8 KB
    __shared__ int eidl[128];
    int tid = threadIdx.x;
    int row0 = blockIdx.x * 128;          // N_EDGES % 128 == 0
    if (tid < 128) eidl[tid] = edge_of_pos[row0 + tid];
    // stage W (B operand): thread handles col c, k-quad k0
    for (int i = tid; i < 1024; i += 256) {
        int c = i >> 4, k0 = (i & 15) * 4;
        ushort4 u;
        u.x = f2bf(W[(k0 + 0) * 64 + c]);
        u.y = f2bf(W[(k0 + 1) * 64 + c]);
        u.z = f2bf(W[(k0 + 2) * 64 + c]);
        u.w = f2bf(W[(k0 + 3) * 64 + c]);
        int lane = (c & 15) + 16 * ((k0 & 15) >> 2);
        int j0 = 4 * ((k0 >> 4) & 1);
        *(ushort4*)&fragB[(c >> 4) * 2 + (k0 >> 5)][lane][j0] = u;
    }
    __syncthreads();
    // stage gathered attr rows (A operand)
    {
        const float4* attr4 = (const float4*)attr;
        for (int i = tid; i < 2048; i += 256) {
            int r = i >> 4, k0 = (i & 15) * 4;
            float4 v = attr4[(long long)eidl[r] * 16 + (k0 >> 2)];
            ushort4 u;
            u.x = f2bf(v.x); u.y = f2bf(v.y); u.z = f2bf(v.z); u.w = f2bf(v.w);
            int lane = (r & 15) + 16 * ((k0 & 15) >> 2);
            int j0 = 4 * ((k0 >> 4) & 1);
            *(ushort4*)&fragA[(r >> 4) * 2 + (k0 >> 5)][lane][j0] = u;
        }
    }
    __syncthreads();
    int w = tid >> 6, l = tid & 63;
    s16x8 a[2][2], bf[4][2];
#pragma unroll
    for (int mt = 0; mt < 2; mt++)
#pragma unroll
        for (int ks = 0; ks < 2; ks++)
            a[mt][ks] = *(const s16x8*)&fragA[(w * 2 + mt) * 2 + ks][l][0];
#pragma unroll
    for (int nt = 0; nt < 4; nt++)
#pragma unroll
        for (int ks = 0; ks < 2; ks++)
            bf[nt][ks] = *(const s16x8*)&fragB[nt * 2 + ks][l][0];
    f32x4 acc[2][4];
#pragma unroll
    for (int mt = 0; mt < 2; mt++)
#pragma unroll
        for (int nt = 0; nt < 4; nt++) {
            f32x4 z = {0.f, 0.f, 0.f, 0.f};
            z = __builtin_amdgcn_mfma_f32_16x16x32_bf16(a[mt][0], bf[nt][0], z, 0, 0, 0);
            acc[mt][nt] = __builtin_amdgcn_mfma_f32_16x16x32_bf16(a[mt][1], bf[nt][1], z, 0, 0, 0);
        }
    // epilogue: += bias, round to bf16, store. D: col = l&15, row = 4*(l>>4)+reg
    int colbase = l & 15, rowq = 4 * (l >> 4);
#pragma unroll
    for (int mt = 0; mt < 2; mt++) {
        int rbase = row0 + (w * 2 + mt) * 16 + rowq;
#pragma unroll
        for (int nt = 0; nt < 4; nt++) {
            int col = nt * 16 + colbase;
            float bias = b[col];
#pragma unroll
            for (int i = 0; i < 4; i++) {
                out[(long long)(rbase + i) * DIM + col] = f2bf(acc[mt][nt][i] + bias);
            }
        }
    }
}

// ---------------- aggregation: wave per node, lane = (feature-quad, edge-slot) ----------------
__global__ __launch_bounds__(256) void agg_kernel(const float* __restrict__ x,
                                                  const int* __restrict__ row_start,
                                                  const int* __restrict__ src_sorted,
                                                  const unsigned short* __restrict__ emb,  // bf16 CSR order
                                                  const float* __restrict__ eps, int layer,
                                                  float* __restrict__ hout,
                                                  float* __restrict__ stats) {
    if (blockIdx.x == 0 && threadIdx.x < 128) stats[threadIdx.x] = 0.0f;
    int node = (blockIdx.x * 256 + threadIdx.x) >> 6;
    int lane = threadIdx.x & 63;
    if (node >= N_NODES) return;
    int fq = lane & 15;       // feature quad
    int eq = lane >> 4;       // edge slot 0..3
    int beg = row_start[node], end = row_start[node + 1];
    const ushort4* emb4 = (const ushort4*)emb;
    const float4* x4 = (const float4*)x;
    float4 acc = make_float4(0.f, 0.f, 0.f, 0.f);
    for (int p0 = beg; p0 < end; p0 += 4) {
        int p = p0 + eq;
        bool valid = (p < end);
        int pc = valid ? p : (end - 1);
        int s = src_sorted[pc];
        ushort4 ev = emb4[(long long)pc * 16 + fq];
        float4 xv = x4[(long long)s * 16 + fq];
        float m0 = gelu_f(xv.x + bf2f(ev.x));
        float m1 = gelu_f(xv.y + bf2f(ev.y));
        float m2 = gelu_f(xv.z + bf2f(ev.z));
        float m3 = gelu_f(xv.w + bf2f(ev.w));
        if (valid) { acc.x += m0; acc.y += m1; acc.z += m2; acc.w += m3; }
    }
    acc.x += __shfl_xor(acc.x, 16, 64); acc.y += __shfl_xor(acc.y, 16, 64);
    acc.z += __shfl_xor(acc.z, 16, 64); acc.w += __shfl_xor(acc.w, 16, 64);
    acc.x += __shfl_xor(acc.x, 32, 64); acc.y += __shfl_xor(acc.y, 32, 64);
    acc.z += __shfl_xor(acc.z, 32, 64); acc.w += __shfl_xor(acc.w, 32, 64);
    if (eq == 0) {
        float e1f = 1.0f + eps[layer];
        float4 xv = x4[(long long)node * 16 + fq];
        float4 o;
        o.x = e1f * xv.x + acc.x; o.y = e1f * xv.y + acc.y;
        o.z = e1f * xv.z + acc.z; o.w = e1f * xv.w + acc.w;
        ((float4*)hout)[(long long)node * 16 + fq] = o;
    }
}

// ---------------- per-node MLP (register-blocked, single shared W buffer) + BN stats ----------------
__global__ __launch_bounds__(256) void mlp_kernel(const float* __restrict__ h_in,
                                                  const float* __restrict__ W1,
                                                  const float* __restrict__ b1,
                                                  const float* __restrict__ W2,
                                                  const float* __restrict__ b2,
                                                  float* __restrict__ h2,
                                                  float* __restrict__ stats) {
    __shared__ float Wl[64][68];    // W1, then reloaded with W2
    __shared__ float T[64][68];     // transposed [k][r]; reused for mid activation
    __shared__ float sredS[4][64];
    __shared__ float sredQ[4][64];
    int tid = threadIdx.x;
    int row0 = blockIdx.x * 64;
    {
        const float4* W14 = (const float4*)W1;
        const float4* h4 = (const float4*)h_in;
        for (int i = tid; i < 1024; i += 256) {
            int r = i >> 4, cq = i & 15;
            *(float4*)&Wl[r][cq * 4] = W14[i];
            int gr = row0 + r;
            float4 v = make_float4(0.f, 0.f, 0.f, 0.f);
            if (gr < N_NODES) v = h4[(long long)gr * 16 + cq];
            int c = cq * 4;
            T[c][r] = v.x; T[c + 1][r] = v.y; T[c + 2][r] = v.z; T[c + 3][r] = v.w;
        }
    }
    __syncthreads();
    int cg = tid & 15, rg = tid >> 4;
    int c0 = cg * 4, r0 = rg * 4;
    float acc[4][4];
    {
        float4 bv = *(const float4*)&b1[c0];
#pragma unroll
        for (int ri = 0; ri < 4; ri++) {
            acc[ri][0] = bv.x; acc[ri][1] = bv.y; acc[ri][2] = bv.z; acc[ri][3] = bv.w;
        }
    }
    for (int k = 0; k < 64; k++) {
        float4 a = *(float4*)&T[k][r0];
        float4 w = *(float4*)&Wl[k][c0];
        float av[4] = {a.x, a.y, a.z, a.w};
#pragma unroll
        for (int ri = 0; ri < 4; ri++) {
            acc[ri][0] += av[ri] * w.x;
            acc[ri][1] += av[ri] * w.y;
            acc[ri][2] += av[ri] * w.z;
            acc[ri][3] += av[ri] * w.w;
        }
    }
    __syncthreads();   // GEMM1 done reading T and Wl
    // write gelu(acc) transposed into T, and reload Wl with W2
#pragma unroll
    for (int ci = 0; ci < 4; ci++) {
        float4 m;
        m.x = gelu_f(acc[0][ci]); m.y = gelu_f(acc[1][ci]);
        m.z = gelu_f(acc[2][ci]); m.w = gelu_f(acc[3][ci]);
        *(float4*)&T[c0 + ci][r0] = m;
    }
    {
        const float4* W24 = (const float4*)W2;
        for (int i = tid; i < 1024; i += 256) {
            int r = i >> 4, cq = i & 15;
            *(float4*)&Wl[r][cq * 4] = W24[i];
        }
    }
    __syncthreads();
    float acc2[4][4];
    {
        float4 bv = *(const float4*)&b2[c0];
#pragma unroll
        for (int ri = 0; ri < 4; ri++) {
            acc2[ri][0] = bv.x; acc2[ri][1] = bv.y; acc2[ri][2] = bv.z; acc2[ri][3] = bv.w;
        }
    }
    for (int k = 0; k < 64; k++) {
        float4 a = *(float4*)&T[k][r0];
        float4 w = *(float4*)&Wl[k][c0];
        float av[4] = {a.x, a.y, a.z, a.w};
#pragma unroll
        for (int ri = 0; ri < 4; ri++) {
            acc2[ri][0] += av[ri] * w.x;
            acc2[ri][1] += av[ri] * w.y;
            acc2[ri][2] += av[ri] * w.z;
            acc2[ri][3] += av[ri] * w.w;
        }
    }
    float4 s = make_float4(0.f, 0.f, 0.f, 0.f);
    float4 q = make_float4(0.f, 0.f, 0.f, 0.f);
#pragma unroll
    for (int ri = 0; ri < 4; ri++) {
        int row = row0 + r0 + ri;
        if (row < N_NODES) {
            float4 o = make_float4(acc2[ri][0], acc2[ri][1], acc2[ri][2], acc2[ri][3]);
            *(float4*)(h2 + (long long)row * DIM + c0) = o;
            s.x += o.x; s.y += o.y; s.z += o.z; s.w += o.w;
            q.x += o.x * o.x; q.y += o.y * o.y; q.z += o.z * o.z; q.w += o.w * o.w;
        }
    }
    s.x += __shfl_xor(s.x, 16, 64); s.y += __shfl_xor(s.y, 16, 64);
    s.z += __shfl_xor(s.z, 16, 64); s.w += __shfl_xor(s.w, 16, 64);
    q.x += __shfl_xor(q.x, 16, 64); q.y += __shfl_xor(q.y, 16, 64);
    q.z += __shfl_xor(q.z, 16, 64); q.w += __shfl_xor(q.w, 16, 64);
    s.x += __shfl_xor(s.x, 32, 64); s.y += __shfl_xor(s.y, 32, 64);
    s.z += __shfl_xor(s.z, 32, 64); s.w += __shfl_xor(s.w, 32, 64);
    q.x += __shfl_xor(q.x, 32, 64); q.y += __shfl_xor(q.y, 32, 64);
    q.z += __shfl_xor(q.z, 32, 64); q.w += __shfl_xor(q.w, 32, 64);
    int wv = tid >> 6;
    if ((tid & 63) < 16) {
        *(float4*)&sredS[wv][c0] = s;
        *(float4*)&sredQ[wv][c0] = q;
    }
    __syncthreads();
    if (tid < 64) {
        float ts = sredS[0][tid] + sredS[1][tid] + sredS[2][tid] + sredS[3][tid];
        float tq = sredQ[0][tid] + sredQ[1][tid] + sredQ[2][tid] + sredQ[3][tid];
        unsafeAtomicAdd(&stats[tid], ts);
        unsafeAtomicAdd(&stats[64 + tid], tq);
    }
}

// ---------------- BN + GELU + residual ----------------
__global__ __launch_bounds__(256) void bn_kernel(const float* __restrict__ x,
                                                 const float* __restrict__ h2,
                                                 const float* __restrict__ stats,
                                                 const float* __restrict__ gamma,
                                                 const float* __restrict__ beta,
                                                 float* __restrict__ out) {
    int i = blockIdx.x * 256 + threadIdx.x;
    if (i >= N_NODES * DIM / 4) return;
    int f4 = i & 15;
    float4 sum = ((const float4*)stats)[f4];
    float4 sq = ((const float4*)(stats + 64))[f4];
    const float invN = 1.0f / (float)N_NODES;
    float mu0 = sum.x * invN, mu1 = sum.y * invN, mu2 = sum.z * invN, mu3 = sum.w * invN;
    float rs0 = rsqrtf(sq.x * invN - mu0 * mu0 + BN_EPS);
    float rs1 = rsqrtf(sq.y * invN - mu1 * mu1 + BN_EPS);
    float rs2 = rsqrtf(sq.z * invN - mu2 * mu2 + BN_EPS);
    float rs3 = rsqrtf(sq.w * invN - mu3 * mu3 + BN_EPS);
    float4 g = ((const float4*)gamma)[f4];
    float4 bt = ((const float4*)beta)[f4];
    float4 hv = ((const float4*)h2)[i];
    float4 xv = ((const float4*)x)[i];
    float4 o;
    o.x = (xv.x + gelu_f((hv.x - mu0) * rs0 * g.x + bt.x)) * INV_SQRT2;
    o.y = (xv.y + gelu_f((hv.y - mu1) * rs1 * g.y + bt.y)) * INV_SQRT2;
    o.z = (xv.z + gelu_f((hv.z - mu2) * rs2 * g.z + bt.z)) * INV_SQRT2;
    o.w = (xv.w + gelu_f((hv.w - mu3) * rs3 * g.w + bt.w)) * INV_SQRT2;
    ((float4*)out)[i] = o;
}

// ---------------- launch ----------------
extern "C" void kernel_launch(void* const* d_in, const int* in_sizes, int n_in,
                              void* d_out, int out_size, void* d_ws, size_t ws_size,
                              hipStream_t stream) {
    const float* x = (const float*)d_in[0];
    const int* ei = (const int*)d_in[1];
    const float* attr = (const float*)d_in[2];
    const float* W_be = (const float*)d_in[3];
    const float* b_be = (const float*)d_in[4];
    const float* eps = (const float*)d_in[5];
    const float* W1 = (const float*)d_in[6];
    const float* b1 = (const float*)d_in[7];
    const float* W2 = (const float*)d_in[8];
    const float* b2 = (const float*)d_in[9];
    const float* gamma = (const float*)d_in[10];
    const float* beta = (const float*)d_in[11];
    float* out = (float*)d_out;

    const size_t emb_bytes = (size_t)N_EDGES * DIM * 2;       // 102.4 MB (bf16)
    const size_t node_bytes = (size_t)N_NODES * DIM * 4;      // 12.8 MB
    const size_t edge_int_bytes = (size_t)N_EDGES * 4;        // 3.2 MB

    char* ws = (char*)d_ws;
    size_t off = 0;
    auto alloc = [&](size_t bytes) { void* p = ws + off; off += (bytes + 255) & ~(size_t)255; return p; };

    unsigned short* emb = (unsigned short*)alloc(emb_bytes);
    float* aggbuf = (float*)alloc(node_bytes);
    float* h2 = (float*)alloc(node_bytes);
    float* xA = (float*)alloc(node_bytes);
    int* src_sorted = (int*)alloc(edge_int_bytes);
    int* edge_of_pos = (int*)alloc(edge_int_bytes);
    int* row_start = (int*)alloc((size_t)(N_NODES + 1) * 4);
    int* cursor = (int*)alloc((size_t)N_NODES * 4);
    int* deg = (int*)alloc((size_t)N_NODES * 4);
    int* part = (int*)alloc(1024);
    float* stats = (float*)alloc(512);

    const int nodeBlocks = (N_NODES + 255) / 256;            // 196
    const int edgeThreadBlocks = (N_EDGES + 255) / 256;      // 3125
    const int beBlocks = N_EDGES / 128;                      // 6250 (exact)
    const int nodeVecBlocks = (N_NODES * DIM / 4 + 255) / 256;  // 3125
    const int aggBlocks = (N_NODES + 3) / 4;                 // 12500 (4 waves/block)
    const int mlpBlocks = (N_NODES + 63) / 64;               // 782

    // --- CSR build ---
    zero_kernel<<<nodeBlocks, 256, 0, stream>>>(deg);
    hist_kernel<<<edgeThreadBlocks, 256, 0, stream>>>(ei, deg);
    scan_partials<<<nodeBlocks, 256, 0, stream>>>(deg, part);
    scan_top<<<1, 256, 0, stream>>>(part, nodeBlocks);
    scan_final<<<nodeBlocks, 256, 0, stream>>>(deg, part, row_start, cursor);
    scatter_kernel<<<edgeThreadBlocks, 256, 0, stream>>>(ei, cursor, edge_of_pos, src_sorted);

    // --- bond encoder: gather attr in CSR order, MFMA, stream bf16 emb ---
    be_gemm<<<beBlocks, 256, 0, stream>>>(attr, W_be, b_be, edge_of_pos, emb);

    for (int l = 0; l < NLAYERS; l++) {
        const float* xin = (l == 0) ? x : ((l == 1) ? xA : out);
        float* xout = (l == 0) ? xA : out;
        agg_kernel<<<aggBlocks, 256, 0, stream>>>(xin, row_start, src_sorted,
                                                  emb, eps, l, aggbuf, stats);
        mlp_kernel<<<mlpBlocks, 256, 0, stream>>>(aggbuf, W1 + l * 4096, b1 + l * 64,
                                                  W2 + l * 4096, b2 + l * 64, h2, stats);
        bn_kernel<<<nodeVecBlocks, 256, 0, stream>>>(xin, h2, stats, gamma + l * 64,
                                                     beta + l * 64, xout);
    }
}